// Round 17
// baseline (50.758 us; speedup 1.0000x reference)
//
#include <hip/hip_runtime.h>
#include <math.h>

namespace {

typedef __fp16 fp16x2 __attribute__((ext_vector_type(2)));    // cvt_pkrtz result type
typedef _Float16 half8v __attribute__((ext_vector_type(8)));  // MFMA operand type
typedef float f32x4 __attribute__((ext_vector_type(4)));

union H8 { half8v v; fp16x2 h2[4]; };

__device__ __forceinline__ void load8(float* r, const float* p) {
    float4 a = *(const float4*)(p);
    float4 b = *(const float4*)(p + 4);
    r[0]=a.x; r[1]=a.y; r[2]=a.z; r[3]=a.w;
    r[4]=b.x; r[5]=b.y; r[6]=b.z; r[7]=b.w;
}

// fp32 -> fp16 hi + exact-residual lo (split precision for MFMA scores)
__device__ __forceinline__ void cvt_split(const float* x, half8v& hi, half8v& lo) {
    H8 h, l;
    #pragma unroll
    for (int i = 0; i < 4; ++i) {
        fp16x2 hh = __builtin_amdgcn_cvt_pkrtz(x[2*i], x[2*i+1]);
        h.h2[i] = hh;
        l.h2[i] = __builtin_amdgcn_cvt_pkrtz(x[2*i]   - (float)hh[0],
                                             x[2*i+1] - (float)hh[1]);
    }
    hi = h.v; lo = l.v;
}

__device__ __forceinline__ half8v cvt_h8(const float* x) {
    H8 h;
    #pragma unroll
    for (int i = 0; i < 4; ++i) h.h2[i] = __builtin_amdgcn_cvt_pkrtz(x[2*i], x[2*i+1]);
    return h.v;
}

__device__ __forceinline__ f32x4 mfma16(half8v a, half8v b, f32x4 c) {
    return __builtin_amdgcn_mfma_f32_16x16x32_f16(a, b, c, 0, 0, 0);
}

__device__ __forceinline__ int clampi(int v, int lo, int hi) {
    return v < lo ? lo : (v > hi ? hi : v);
}

// MFMA local attention. Wave = 16 px of one row; block = 4 waves = 64 px;
// grid = 2*128*2 = 512 blocks, XCD-banded. Scores: S[16px,20col] per di via
// 2 n-tiles of mfma_f32_16x16x32_f16 x 8 K-steps, fp16 SPLIT (Ah*Bh + Al*Bh
// + Ah*Bl -> err ~1e-5). Softmax via per-wave LDS transpose (same-wave LDS
// is program-ordered -> NO barriers anywhere). PV: W(16x32 banded, fp16) x
// V(32x64 fp16) -> 4 n-tiles x 1 K-step per di. Zero-pad semantics: clamped
// loads; score masked to exactly 0 pre-softmax (exp(0-mx) stays in den);
// PV-weight masked to 0. Self slot handled in fp32 throughout.
// Fragment layouts (guide/m89): A[m][k]: m=l&15,k=8*(l>>4)+j; B[k][n]:
// n=l&15,k=8*(l>>4)+j; D[m][n]: n=l&15, m=4*(l>>4)+reg.
__global__ __launch_bounds__(256)
void local_attn_kernel(const float* __restrict__ mainp,
                       const float* __restrict__ mainv,
                       const float* __restrict__ refp,
                       const float* __restrict__ refv,
                       float* __restrict__ outp)
{
    const int l  = threadIdx.x & 63;
    const int wv = threadIdx.x >> 6;          // wave 0..3
    const int ln = l & 15;
    const int kg = l >> 4;                    // k-group 0..3

    const int bid = blockIdx.x;               // 0..511
    const int wid = ((bid & 7) << 6) | (bid >> 3);  // 8 XCD bands of 64
    const int strip = wid & 1;
    const int h = (wid >> 1) & 127;
    const int b = wid >> 8;
    const int w0 = strip * 64 + wv * 16;      // wave's first pixel

    __shared__ float SW[4][16][28];           // per-wave [px][25 w | wself | invden | pad]
    float (*sw)[28] = SW[wv];

    // ---------------- phase 1: A fragments (main, hi/lo) + self ----------
    half8v Ah[8], Al[8];
    float self = 0.f;
    {
        const float* mp = mainp + ((size_t)((b*128 + h)*128) + w0 + ln) * 256 + kg*8;
        #pragma unroll
        for (int kk = 0; kk < 8; ++kk) {
            float r[8]; load8(r, mp + kk*32);
            #pragma unroll
            for (int c = 0; c < 8; ++c) self = fmaf(r[c], r[c], self);
            cvt_split(r, Ah[kk], Al[kk]);
        }
        self += __shfl_xor(self, 16);
        self += __shfl_xor(self, 32);         // lane now has full self for px=ln
    }

    // ---------------- phase 2: score MFMAs, S -> LDS ---------------------
    #pragma unroll 1
    for (int di = 0; di < 5; ++di) {
        const int hhc = clampi(h + di - 2, 0, 127);
        const float* rp = refp + ((size_t)((b*128 + hhc)*128)) * 256 + kg*8;
        const int c0c = clampi(w0 - 2 + ln, 0, 127);
        const int c1c = clampi(w0 + 14 + ln, 0, 127);
        f32x4 a0{0.f,0.f,0.f,0.f}, b0{0.f,0.f,0.f,0.f};
        f32x4 a1{0.f,0.f,0.f,0.f}, b1{0.f,0.f,0.f,0.f};
        #pragma unroll
        for (int kk = 0; kk < 8; ++kk) {
            float r0[8], r1[8];
            load8(r0, rp + (size_t)c0c*256 + kk*32);
            load8(r1, rp + (size_t)c1c*256 + kk*32);
            half8v B0h, B0l, B1h, B1l;
            cvt_split(r0, B0h, B0l);
            cvt_split(r1, B1h, B1l);
            a0 = mfma16(Ah[kk], B0h, a0);
            b0 = mfma16(Al[kk], B0h, b0);
            b0 = mfma16(Ah[kk], B0l, b0);
            a1 = mfma16(Ah[kk], B1h, a1);
            b1 = mfma16(Al[kk], B1h, b1);
            b1 = mfma16(Ah[kk], B1l, b1);
        }
        #pragma unroll
        for (int reg = 0; reg < 4; ++reg) {
            const int m = kg*4 + reg;
            const int d0 = ln - m;            // dj = n - m, tile0 n=ln
            if (d0 >= 0 && d0 <= 4) sw[m][di*5 + d0] = a0[reg] + b0[reg];
            const int d1 = ln + 16 - m;       // tile1 n=16+ln
            if (d1 >= 0 && d1 <= 4) sw[m][di*5 + d1] = a1[reg] + b1[reg];
        }
    }

    // ---------------- phase 3: softmax (lane owns px=ln; kg-redundant) ---
    {
        float s[25];
        #pragma unroll
        for (int k = 0; k < 25; ++k) s[k] = sw[ln][k];
        const int pxg = w0 + ln;
        float mx = self;
        #pragma unroll
        for (int di = 0; di < 5; ++di) {
            const bool rok = (unsigned)(h + di - 2) < 128u;
            #pragma unroll
            for (int d = 0; d < 5; ++d) {
                const bool ok = rok && (unsigned)(pxg + d - 2) < 128u;
                s[di*5+d] = ok ? s[di*5+d] : 0.f;   // zero-pad score semantics
                mx = fmaxf(mx, s[di*5+d]);
            }
        }
        float den = __expf(self - mx);
        const float wself = den;
        #pragma unroll
        for (int di = 0; di < 5; ++di) {
            const bool rok = (unsigned)(h + di - 2) < 128u;
            #pragma unroll
            for (int d = 0; d < 5; ++d) {
                const float e = __expf(s[di*5+d] - mx);
                den += e;                             // padded slots keep exp(0-mx)
                const bool ok = rok && (unsigned)(pxg + d - 2) < 128u;
                s[di*5+d] = ok ? e : 0.f;             // but contribute 0 value
            }
        }
        #pragma unroll
        for (int k = 0; k < 25; ++k) sw[ln][k] = s[k];
        sw[ln][25] = wself;
        sw[ln][26] = 1.f / den;
    }

    // ---------------- phase 4: PV MFMAs ----------------------------------
    f32x4 cv0{0.f,0.f,0.f,0.f}, cv1{0.f,0.f,0.f,0.f};
    f32x4 cv2{0.f,0.f,0.f,0.f}, cv3{0.f,0.f,0.f,0.f};
    #pragma unroll 1
    for (int di = 0; di < 5; ++di) {
        // W A-frag: m=ln, k = kg*8+j (k-slot = window col idx); W=w[di*5+(k-m)]
        float wr[8];
        #pragma unroll
        for (int j = 0; j < 8; ++j) {
            const int d  = kg*8 + j - ln;
            const int dc = clampi(d, 0, 4);
            const float wv_ = sw[ln][di*5 + dc];
            wr[j] = (d == dc) ? wv_ : 0.f;
        }
        const half8v Wf = cvt_h8(wr);

        const int hhc = clampi(h + di - 2, 0, 127);
        const float* vp = refv + ((size_t)((b*128 + hhc)*128)) * 64;
        #pragma unroll
        for (int t = 0; t < 4; ++t) {
            float vr[8];
            #pragma unroll
            for (int j = 0; j < 8; ++j) {
                const int colc = clampi(w0 - 2 + kg*8 + j, 0, 127);
                vr[j] = vp[(size_t)colc*64 + t*16 + ln];
            }
            const half8v Vf = cvt_h8(vr);
            if (t == 0) cv0 = mfma16(Wf, Vf, cv0);
            if (t == 1) cv1 = mfma16(Wf, Vf, cv1);
            if (t == 2) cv2 = mfma16(Wf, Vf, cv2);
            if (t == 3) cv3 = mfma16(Wf, Vf, cv3);
        }
    }

    // ---------------- epilogue: + wself*mainv, * invden, store -----------
    #pragma unroll
    for (int reg = 0; reg < 4; ++reg) {
        const int m = kg*4 + reg;
        const float ws  = sw[m][25];
        const float inv = sw[m][26];
        const size_t pbase = ((size_t)((b*128 + h)*128) + w0 + m) * 64;
        #pragma unroll
        for (int t = 0; t < 4; ++t) {
            const float cvr = (t==0?cv0[reg]:t==1?cv1[reg]:t==2?cv2[reg]:cv3[reg]);
            const float mv = mainv[pbase + t*16 + ln];
            outp[pbase + t*16 + ln] = (cvr + ws * mv) * inv;
        }
    }
}

} // namespace

extern "C" void kernel_launch(void* const* d_in, const int* in_sizes, int n_in,
                              void* d_out, int out_size, void* d_ws, size_t ws_size,
                              hipStream_t stream)
{
    const float* mainp = (const float*)d_in[0];
    const float* mainv = (const float*)d_in[1];
    const float* refp  = (const float*)d_in[2];
    const float* refv  = (const float*)d_in[3];
    float* outp = (float*)d_out;

    dim3 grid(512);    // 2 batch x 128 rows x 2 strips, XCD-banded swizzle
    dim3 block(256);   // 4 waves x 16 px
    hipLaunchKernelGGL(local_attn_kernel, grid, block, 0, stream,
                       mainp, mainv, refp, refv, outp);
}